// Round 7
// baseline (235.689 us; speedup 1.0000x reference)
//
#include <hip/hip_runtime.h>
#include <hip/hip_bf16.h>

#define NBINS 600
#define NCOPIES 32  // c = tid&31 -> lane's atomic always hits bank c

#define ATOM4(v)                                   \
    atomicAdd(&h[(v).x * NCOPIES + c], 1);         \
    atomicAdd(&h[(v).y * NCOPIES + c], 1);         \
    atomicAdd(&h[(v).z * NCOPIES + c], 1);         \
    atomicAdd(&h[(v).w * NCOPIES + c], 1);

#define SUM4(v) s += (v).x + (v).y + (v).z + (v).w;

// DIAGNOSTIC probe: identical launch shape, LDS footprint and load loop as the
// histogram kernel, but atomics replaced by a register sum (stored -> not DCE'd).
// Measures the pure memory-path time of this structure.
__global__ __launch_bounds__(512) void bincount_probe(
        const int* __restrict__ x, int n, int* __restrict__ sink) {
    __shared__ int h[NBINS * NCOPIES];  // same 76.8 KB -> same 2 blocks/CU
    for (int i = threadIdx.x; i < NBINS * NCOPIES; i += 512) h[i] = 0;
    __syncthreads();
    const int n4 = n >> 2;
    const int4* __restrict__ x4 = (const int4*)x;
    const int nth = gridDim.x * 512;
    const int base = blockIdx.x * 512 + threadIdx.x;
    const int per = n4 / nth;
    int s = 0;
    if (per * nth == n4 && (per & 3) == 0) {
        int4 v0 = x4[base];
        int4 v1 = x4[base + nth];
        int4 v2 = x4[base + 2 * nth];
        int4 v3 = x4[base + 3 * nth];
        for (int k = 4; k < per; k += 4) {
            int4 p0 = x4[base + (k + 0) * nth];
            int4 p1 = x4[base + (k + 1) * nth];
            int4 p2 = x4[base + (k + 2) * nth];
            int4 p3 = x4[base + (k + 3) * nth];
            SUM4(v0); SUM4(v1); SUM4(v2); SUM4(v3);
            v0 = p0; v1 = p1; v2 = p2; v3 = p3;
        }
        SUM4(v0); SUM4(v1); SUM4(v2); SUM4(v3);
    } else {
        for (int i = base; i < n4; i += nth) { int4 v = x4[i]; SUM4(v); }
    }
    h[threadIdx.x] = s;   // keep LDS alive so occupancy matches the real kernel
    __syncthreads();
    sink[base] = h[threadIdx.x ^ 1];
}

// Histogram kernel, DOUBLE-PASS (diagnostic): counts everything twice, epilogue
// stores s>>1 (exact: both passes identical per block -> per-block partials even).
// Purpose: push this dispatch above the 77us fill kernels into rocprof top-5.
__global__ __launch_bounds__(512) void bincount_part2(
        const int* __restrict__ x, int n, int* __restrict__ part) {
    __shared__ int h[NBINS * NCOPIES];
    for (int i = threadIdx.x; i < NBINS * NCOPIES; i += 512) h[i] = 0;
    __syncthreads();

    const int c = threadIdx.x & (NCOPIES - 1);
    const int n4 = n >> 2;
    const int4* __restrict__ x4 = (const int4*)x;
    const int nth = gridDim.x * 512;
    const int base = blockIdx.x * 512 + threadIdx.x;
    const int per = n4 / nth;

    for (int pass = 0; pass < 2; ++pass) {
        if (per * nth == n4 && (per & 3) == 0) {
            int4 v0 = x4[base];
            int4 v1 = x4[base + nth];
            int4 v2 = x4[base + 2 * nth];
            int4 v3 = x4[base + 3 * nth];
            for (int k = 4; k < per; k += 4) {
                int4 p0 = x4[base + (k + 0) * nth];
                int4 p1 = x4[base + (k + 1) * nth];
                int4 p2 = x4[base + (k + 2) * nth];
                int4 p3 = x4[base + (k + 3) * nth];
                ATOM4(v0); ATOM4(v1); ATOM4(v2); ATOM4(v3);
                v0 = p0; v1 = p1; v2 = p2; v3 = p3;
            }
            ATOM4(v0); ATOM4(v1); ATOM4(v2); ATOM4(v3);
        } else {
            for (int i = base; i < n4; i += nth) {
                int4 v = x4[i];
                ATOM4(v);
            }
        }
        if (blockIdx.x == 0) {  // scalar tail, counted twice like everything else
            for (int t = (n4 << 2) + (int)threadIdx.x; t < n; t += 512)
                atomicAdd(&h[x[t] * NCOPIES + c], 1);
        }
        __asm__ volatile("" ::: "memory");  // forbid cross-pass load CSE
    }

    __syncthreads();
    for (int b = threadIdx.x; b < NBINS; b += 512) {
        int s = 0;
        #pragma unroll
        for (int j = 0; j < NCOPIES; ++j)
            s += h[b * NCOPIES + ((j + threadIdx.x) & (NCOPIES - 1))];
        part[blockIdx.x * NBINS + b] = s >> 1;  // exact halving of double count
    }
}

__global__ __launch_bounds__(64) void bincount_reduce(
        const int* __restrict__ part, int nblocks, int* __restrict__ out) {
    const int bin = blockIdx.x;
    const int t = threadIdx.x;
    int s = 0;
    for (int b = t; b < nblocks; b += 64)
        s += part[b * NBINS + bin];
    #pragma unroll
    for (int off = 32; off > 0; off >>= 1)
        s += __shfl_down(s, off, 64);
    if (t == 0) out[bin] = s;
}

extern "C" void kernel_launch(void* const* d_in, const int* in_sizes, int n_in,
                              void* d_out, int out_size, void* d_ws, size_t ws_size,
                              hipStream_t stream) {
    const int* x = (const int*)d_in[0];
    int* out = (int*)d_out;
    int* part = (int*)d_ws;
    const int n = in_sizes[0];

    int nblocks = 512;
    while ((size_t)nblocks * NBINS * sizeof(int) > ws_size && nblocks > 64)
        nblocks >>= 1;

    // probe sink lives past the partials region
    if (ws_size >= (8u << 20)) {
        int* sink = (int*)((char*)d_ws + (4u << 20));
        bincount_probe<<<nblocks, 512, 0, stream>>>(x, n, sink);
    }
    bincount_part2<<<nblocks, 512, 0, stream>>>(x, n, part);
    bincount_reduce<<<NBINS, 64, 0, stream>>>(part, nblocks, out);
}

// Round 8
// 191.892 us; speedup vs baseline: 1.2282x; 1.2282x over previous
//
#include <hip/hip_runtime.h>
#include <hip/hip_bf16.h>

#define NBINS 600
#define NCOPIES 32  // c = tid&31 -> lane's atomic ALWAYS hits bank c: zero bank conflicts

#define ATOM4(v)                                   \
    atomicAdd(&h[(v).x * NCOPIES + c], 1);         \
    atomicAdd(&h[(v).y * NCOPIES + c], 1);         \
    atomicAdd(&h[(v).z * NCOPIES + c], 1);         \
    atomicAdd(&h[(v).w * NCOPIES + c], 1);

// Kernel A: per-block 32-copy LDS histogram -> plain-store partials (idempotent
// under any graph-replay overlap: no global atomics, full overwrite of its ws
// slice every call). Measured (r7 diagnostic): load path ~22us (= HBM floor),
// LDS atomics overlap loads (~+5us), total ~25-30us.
__global__ __launch_bounds__(512) void bincount_part(
        const int* __restrict__ x, int n, int* __restrict__ part) {
    __shared__ int h[NBINS * NCOPIES];  // 76800 B -> 2 blocks/CU, 16 waves/CU

    for (int i = threadIdx.x; i < NBINS * NCOPIES; i += 512) h[i] = 0;
    __syncthreads();

    const int c = threadIdx.x & (NCOPIES - 1);
    const int n4 = n >> 2;
    const int4* __restrict__ x4 = (const int4*)x;
    const int nth = gridDim.x * 512;
    const int base = blockIdx.x * 512 + threadIdx.x;
    const int per = n4 / nth;

    if (per * nth == n4 && (per & 3) == 0) {
        // fast path (n4 divides evenly, per % 4 == 0): prefetch 4 int4 ahead
        int4 v0 = x4[base];
        int4 v1 = x4[base + nth];
        int4 v2 = x4[base + 2 * nth];
        int4 v3 = x4[base + 3 * nth];
        for (int k = 4; k < per; k += 4) {
            int4 p0 = x4[base + (k + 0) * nth];
            int4 p1 = x4[base + (k + 1) * nth];
            int4 p2 = x4[base + (k + 2) * nth];
            int4 p3 = x4[base + (k + 3) * nth];
            ATOM4(v0); ATOM4(v1); ATOM4(v2); ATOM4(v3);
            v0 = p0; v1 = p1; v2 = p2; v3 = p3;
        }
        ATOM4(v0); ATOM4(v1); ATOM4(v2); ATOM4(v3);
    } else {
        for (int i = base; i < n4; i += nth) {
            int4 v = x4[i];
            ATOM4(v);
        }
    }
    // scalar tail (n % 4), block 0 only
    if (blockIdx.x == 0) {
        for (int t = (n4 << 2) + (int)threadIdx.x; t < n; t += 512)
            atomicAdd(&h[x[t] * NCOPIES + c], 1);
    }

    __syncthreads();

    // per-block partial: rotate copy index by lane (avoid 64-way broadcast bank hit)
    for (int b = threadIdx.x; b < NBINS; b += 512) {
        int s = 0;
        #pragma unroll
        for (int j = 0; j < NCOPIES; ++j)
            s += h[b * NCOPIES + ((j + threadIdx.x) & (NCOPIES - 1))];
        part[blockIdx.x * NBINS + b] = s;  // plain store, coalesced
    }
}

// Kernel B: one wave per bin; shuffle-reduce over block partials; plain store.
// 1.2 MB read, L2-resident, ~2-3us.
__global__ __launch_bounds__(64) void bincount_reduce(
        const int* __restrict__ part, int nblocks, int* __restrict__ out) {
    const int bin = blockIdx.x;
    const int t = threadIdx.x;
    int s = 0;
    for (int b = t; b < nblocks; b += 64)
        s += part[b * NBINS + bin];
    #pragma unroll
    for (int off = 32; off > 0; off >>= 1)
        s += __shfl_down(s, off, 64);
    if (t == 0) out[bin] = s;
}

extern "C" void kernel_launch(void* const* d_in, const int* in_sizes, int n_in,
                              void* d_out, int out_size, void* d_ws, size_t ws_size,
                              hipStream_t stream) {
    const int* x = (const int*)d_in[0];
    int* out = (int*)d_out;
    int* part = (int*)d_ws;
    const int n = in_sizes[0];

    int nblocks = 512;  // 2 blocks/CU on 256 CUs, all resident
    while ((size_t)nblocks * NBINS * sizeof(int) > ws_size && nblocks > 64)
        nblocks >>= 1;

    bincount_part<<<nblocks, 512, 0, stream>>>(x, n, part);
    bincount_reduce<<<NBINS, 64, 0, stream>>>(part, nblocks, out);
}